// Round 5
// baseline (239.517 us; speedup 1.0000x reference)
//
#include <hip/hip_runtime.h>

// ConvSurface: out[m,f,k] = max_s relu( (point_{m,f,s} - center_{m,f}) . W_k + b_k )
// Lane = kernel k. Block = 16 faces x 8 meshes (128 pairs), 4 waves; wave w
// owns faces [4w, 4w+4) across all 8 meshes (beta/gamma reused 8x per face).
// R5: LDS staging — load phase does coalesced vector loads of corners/centers/
// beta/gamma into LDS; compute phase uses uniform ds_read_b128 broadcasts
// instead of s_loads (kills the lgkmcnt(0) K$ drain stalls of R4).
// Algebra: alpha+beta+gamma==1 => p.W = a1 + beta*(a2-a1) + gamma*(a3-a1);
// bias/center-dot/relu folded outside the sample max (monotone).

#define NM 8
#define NF 16384
#define NK 64
#define TF 16          // faces per block
#define PAD_C 28       // corner floats per (m,f), padded 27->28 for b128 align

// constexpr-index component pick from a float4 array (folds after unroll)
#define Q4(a, e) ((e) % 4 == 0 ? a[(e) / 4].x : (e) % 4 == 1 ? a[(e) / 4].y : \
                  (e) % 4 == 2 ? a[(e) / 4].z : a[(e) / 4].w)

__global__ __launch_bounds__(256, 4) void conv_surface_kernel(
    const float* __restrict__ centers,   // [M,F,3]
    const float* __restrict__ nc,        // [M,F,3,3,3]
    const float* __restrict__ beta,      // [F,24]
    const float* __restrict__ gammav,    // [F,24]
    const float* __restrict__ W,         // [64,3]
    const float* __restrict__ b,         // [64]
    float* __restrict__ out)             // [M,F,64]
{
    __shared__ float s_corners[NM * TF * PAD_C];  // 14336 B
    __shared__ float s_centers[NM * TF * 4];      //  2048 B (padded 3->4)
    __shared__ float s_bg[TF * 48];               //  3072 B (24 beta | 24 gamma)

    const int tid = threadIdx.x;
    const int f0  = blockIdx.x * TF;

    // ---------------- load phase (coalesced global -> LDS) ----------------
#pragma unroll
    for (int m = 0; m < NM; ++m) {
        const float* __restrict__ src = nc + ((size_t)m * NF + f0) * 27;
        for (int j = tid; j < TF * 27; j += 256) {        // 432 floats
            const int p = j / 27, e = j - p * 27;
            s_corners[(m * TF + p) * PAD_C + e] = src[j];
        }
        const float* __restrict__ csrc = centers + ((size_t)m * NF + f0) * 3;
        if (tid < TF * 3) {                                // 48 floats
            const int p = tid / 3, e = tid - p * 3;
            s_centers[(m * TF + p) * 4 + e] = csrc[tid];
        }
    }
    for (int j = tid; j < TF * 24; j += 256) {             // 384 + 384 floats
        const int fi = j / 24, e = j - fi * 24;
        s_bg[fi * 48 + e]      = beta  [(size_t)f0 * 24 + j];
        s_bg[fi * 48 + 24 + e] = gammav[(size_t)f0 * 24 + j];
    }
    __syncthreads();

    // ---------------- compute phase ----------------
    const int lane = tid & 63;
    const int wav  = __builtin_amdgcn_readfirstlane(tid >> 6);

    const float w0 = W[lane * 3 + 0];
    const float w1 = W[lane * 3 + 1];
    const float w2 = W[lane * 3 + 2];
    const float bk = b[lane];

    for (int fo = 0; fo < 4; ++fo) {
        const int fi = wav * 4 + fo;

        // face sample coefficients: uniform b128 broadcast reads, reused 8x
        const float4* __restrict__ bg4 = (const float4*)(s_bg + fi * 48);
        float4 bq[6], gq[6];
#pragma unroll
        for (int q = 0; q < 6; ++q) { bq[q] = bg4[q]; gq[q] = bg4[6 + q]; }

#pragma unroll 2
        for (int m = 0; m < NM; ++m) {
            const float4 c = *(const float4*)(s_centers + (m * TF + fi) * 4);
            const float4* __restrict__ tb =
                (const float4*)(s_corners + (m * TF + fi) * PAD_C);
            float4 tq[7];
#pragma unroll
            for (int q = 0; q < 7; ++q) tq[q] = tb[q];    // 27 floats (+1 pad)

            const float cdot = c.x * w0 + c.y * w1 + c.z * w2;

            float smp[24];
#pragma unroll
            for (int n = 0; n < 3; ++n) {
                const float a1 = Q4(tq, n * 9 + 0) * w0 + Q4(tq, n * 9 + 1) * w1 + Q4(tq, n * 9 + 2) * w2;
                const float a2 = Q4(tq, n * 9 + 3) * w0 + Q4(tq, n * 9 + 4) * w1 + Q4(tq, n * 9 + 5) * w2;
                const float a3 = Q4(tq, n * 9 + 6) * w0 + Q4(tq, n * 9 + 7) * w1 + Q4(tq, n * 9 + 8) * w2;
                const float e2 = a2 - a1;
                const float e3 = a3 - a1;
#pragma unroll
                for (int j = 0; j < 8; ++j) {
                    const int s = n + 3 * j;               // reference order n = s%3
                    smp[s] = fmaf(Q4(bq, s), e2, fmaf(Q4(gq, s), e3, a1));
                }
            }
            // max3-friendly reduction: 24 -> 8 -> 3 -> 1
            float t8[8];
#pragma unroll
            for (int i = 0; i < 8; ++i)
                t8[i] = fmaxf(fmaxf(smp[3 * i], smp[3 * i + 1]), smp[3 * i + 2]);
            const float ma = fmaxf(fmaxf(t8[0], t8[1]), t8[2]);
            const float mb = fmaxf(fmaxf(t8[3], t8[4]), t8[5]);
            const float mc = fmaxf(t8[6], t8[7]);
            const float mx = fmaxf(fmaxf(ma, mb), mc);

            out[((size_t)m * NF + f0 + fi) * NK + lane] =
                fmaxf(mx + (bk - cdot), 0.0f);
        }
    }
}

extern "C" void kernel_launch(void* const* d_in, const int* in_sizes, int n_in,
                              void* d_out, int out_size, void* d_ws, size_t ws_size,
                              hipStream_t stream) {
    const float* centers = (const float*)d_in[0];
    // d_in[1] = ring_n  (unused by the reference math)
    const float* nc      = (const float*)d_in[2];
    // d_in[3] = alpha   (unused: alpha = 1 - beta - gamma)
    const float* beta    = (const float*)d_in[4];
    const float* gammav  = (const float*)d_in[5];
    const float* W       = (const float*)d_in[6];
    const float* b       = (const float*)d_in[7];
    float* out = (float*)d_out;

    dim3 grid(NF / TF), block(256);   // 1024 blocks, 4 waves each
    hipLaunchKernelGGL(conv_surface_kernel, grid, block, 0, stream,
                       centers, nc, beta, gammav, W, b, out);
}

// Round 6
// 212.943 us; speedup vs baseline: 1.1248x; 1.1248x over previous
//
#include <hip/hip_runtime.h>

// ConvSurface: out[m,f,k] = max_s relu( (point_{m,f,s} - center_{m,f}) . W_k + b_k )
// Lane = kernel k. Block = 128 threads (2 waves), 8 faces; wave w owns faces
// [4w,4w+4) across all 8 meshes. LDS staging of corners/centers/beta/gamma
// (coalesced global loads, uniform ds_read_b128 broadcasts in compute).
// R6: spill-proof rewrite of R5 — ALL compute state is named scalars (no
// register arrays -> nothing demotable to scratch), beta/gamma transposed
// per-neighbor in LDS so they are consumed as 4 transient b128 reads,
// corners padded to per-corner float4. 128-thr blocks, cap 128 VGPR.
// Algebra: alpha+beta+gamma==1 => p.W = a1 + beta*(a2-a1) + gamma*(a3-a1);
// bias/center-dot/relu folded outside the sample max (monotone).

#define NM 8
#define NF 16384
#define NK 64
#define FB 8           // faces per block

__global__ __launch_bounds__(128, 4) void conv_surface_kernel(
    const float* __restrict__ centers,   // [M,F,3]
    const float* __restrict__ nc,        // [M,F,3,3,3]
    const float* __restrict__ beta,      // [F,24]
    const float* __restrict__ gammav,    // [F,24]
    const float* __restrict__ W,         // [64,3]
    const float* __restrict__ b,         // [64]
    float* __restrict__ out)             // [M,F,64]
{
    __shared__ float s_c[NM * FB * 9 * 4];   // corners, per-corner float4: 9216 B
    __shared__ float s_cent[NM * FB * 4];    // centers padded:              1024 B
    __shared__ float s_bg[FB * 3 * 16];      // per (f,n): 8 beta | 8 gamma: 1536 B

    const int tid = threadIdx.x;
    const int f0  = blockIdx.x * FB;

    // ---------------- load phase (coalesced global -> LDS) ----------------
    for (int j = tid; j < NM * FB * 27; j += 128) {          // 1728 floats
        const int m = j / (FB * 27);
        const int r = j - m * (FB * 27);
        const int p = r / 27, e = r - p * 27;
        const int corner = e / 3, comp = e - corner * 3;
        s_c[((m * FB + p) * 9 + corner) * 4 + comp] =
            nc[((size_t)m * NF + f0) * 27 + r];
    }
    for (int j = tid; j < NM * FB * 3; j += 128) {           // 192 floats
        const int m = j / (FB * 3);
        const int r = j - m * (FB * 3);
        const int p = r / 3, comp = r - p * 3;
        s_cent[(m * FB + p) * 4 + comp] =
            centers[((size_t)m * NF + f0) * 3 + r];
    }
    for (int j = tid; j < FB * 24; j += 128) {               // 192 + 192 floats
        const int fi = j / 24, s = j - fi * 24;
        const int n = s % 3, jj = s / 3;
        s_bg[(fi * 3 + n) * 16 + jj]     = beta  [(size_t)(f0 + fi) * 24 + s];
        s_bg[(fi * 3 + n) * 16 + 8 + jj] = gammav[(size_t)(f0 + fi) * 24 + s];
    }
    __syncthreads();

    // ---------------- compute phase ----------------
    const int lane = tid & 63;
    const int wav  = __builtin_amdgcn_readfirstlane(tid >> 6);

    const float w0 = W[lane * 3 + 0];
    const float w1 = W[lane * 3 + 1];
    const float w2 = W[lane * 3 + 2];
    const float bk = b[lane];

#pragma unroll 1
    for (int fo = 0; fo < 4; ++fo) {
        const int fi = wav * 4 + fo;
        const float4* __restrict__ bgp = (const float4*)(s_bg) + fi * 12;

#pragma unroll 2
        for (int m = 0; m < NM; ++m) {
            const float4* __restrict__ tp = (const float4*)(s_c) + (m * FB + fi) * 9;
            const float4 c = *((const float4*)(s_cent) + (m * FB + fi));
            const float cdot = c.x * w0 + c.y * w1 + c.z * w2;

            float mx = -3.4e38f;
#pragma unroll
            for (int n = 0; n < 3; ++n) {
                const float4 t0 = tp[n * 3 + 0];
                const float4 t1 = tp[n * 3 + 1];
                const float4 t2 = tp[n * 3 + 2];
                const float a1 = t0.x * w0 + t0.y * w1 + t0.z * w2;
                const float a2 = t1.x * w0 + t1.y * w1 + t1.z * w2;
                const float a3 = t2.x * w0 + t2.y * w1 + t2.z * w2;
                const float e2 = a2 - a1;
                const float e3 = a3 - a1;

                const float4 b0 = bgp[n * 4 + 0];   // beta  s = n+3*{0..3}
                const float4 b1 = bgp[n * 4 + 1];   // beta  s = n+3*{4..7}
                const float4 g0 = bgp[n * 4 + 2];   // gamma s = n+3*{0..3}
                const float4 g1 = bgp[n * 4 + 3];   // gamma s = n+3*{4..7}

                const float v0 = fmaf(b0.x, e2, fmaf(g0.x, e3, a1));
                const float v1 = fmaf(b0.y, e2, fmaf(g0.y, e3, a1));
                const float v2 = fmaf(b0.z, e2, fmaf(g0.z, e3, a1));
                const float v3 = fmaf(b0.w, e2, fmaf(g0.w, e3, a1));
                const float v4 = fmaf(b1.x, e2, fmaf(g1.x, e3, a1));
                const float v5 = fmaf(b1.y, e2, fmaf(g1.y, e3, a1));
                const float v6 = fmaf(b1.z, e2, fmaf(g1.z, e3, a1));
                const float v7 = fmaf(b1.w, e2, fmaf(g1.w, e3, a1));

                const float p0 = fmaxf(fmaxf(v0, v1), fmaxf(v2, v3));
                const float p1 = fmaxf(fmaxf(v4, v5), fmaxf(v6, v7));
                mx = fmaxf(mx, fmaxf(p0, p1));
            }

            out[((size_t)m * NF + f0 + fi) * NK + lane] =
                fmaxf(mx + (bk - cdot), 0.0f);
        }
    }
}

extern "C" void kernel_launch(void* const* d_in, const int* in_sizes, int n_in,
                              void* d_out, int out_size, void* d_ws, size_t ws_size,
                              hipStream_t stream) {
    const float* centers = (const float*)d_in[0];
    // d_in[1] = ring_n  (unused by the reference math)
    const float* nc      = (const float*)d_in[2];
    // d_in[3] = alpha   (unused: alpha = 1 - beta - gamma)
    const float* beta    = (const float*)d_in[4];
    const float* gammav  = (const float*)d_in[5];
    const float* W       = (const float*)d_in[6];
    const float* b       = (const float*)d_in[7];
    float* out = (float*)d_out;

    dim3 grid(NF / FB), block(128);   // 2048 blocks = 8 blocks/CU exactly
    hipLaunchKernelGGL(conv_surface_kernel, grid, block, 0, stream,
                       centers, nc, beta, gammav, W, b, out);
}

// Round 7
// 42.593 us; speedup vs baseline: 5.6234x; 4.9995x over previous
//
#include <hip/hip_runtime.h>

// ConvSurface: out[m,f,k] = max_s relu( (point_{m,f,s} - center_{m,f}) . W_k + b_k )
// Lane = kernel k (64 = wave64). One wave per FACE, m-loop over 8 meshes.
// R7: R4 dataflow, but corners/centers go through VMEM (per-lane broadcast
// loads, address intentionally divergent) into a manually double-buffered
// A/B named-register set: mesh m+1's 30 loads are in flight (vmcnt-counted)
// while mesh m computes. beta/gamma stay SMEM/SGPR (uniform, 48 regs, reused
// 8x, one scalar operand per FMA). No LDS, no private arrays -> no scratch.
// Algebra: alpha+beta+gamma==1 => p.W = a1 + beta*(a2-a1) + gamma*(a3-a1);
// bias/center-dot/relu folded outside the sample max (monotone).

#define NM 8
#define NF 16384
#define NK 64

#define DECL_SET(P) \
    float P##0,P##1,P##2,P##3,P##4,P##5,P##6,P##7,P##8,P##9,P##10,P##11,P##12,P##13, \
          P##14,P##15,P##16,P##17,P##18,P##19,P##20,P##21,P##22,P##23,P##24,P##25,P##26, \
          P##cx,P##cy,P##cz;

#define LOADC(P, m) do { \
    const float* __restrict__ p_ = nc + ((size_t)(m) * NF + fdiv) * 27; \
    P##0=p_[0];   P##1=p_[1];   P##2=p_[2];   P##3=p_[3];   P##4=p_[4];   P##5=p_[5]; \
    P##6=p_[6];   P##7=p_[7];   P##8=p_[8];   P##9=p_[9];   P##10=p_[10]; P##11=p_[11]; \
    P##12=p_[12]; P##13=p_[13]; P##14=p_[14]; P##15=p_[15]; P##16=p_[16]; P##17=p_[17]; \
    P##18=p_[18]; P##19=p_[19]; P##20=p_[20]; P##21=p_[21]; P##22=p_[22]; P##23=p_[23]; \
    P##24=p_[24]; P##25=p_[25]; P##26=p_[26]; \
    const float* __restrict__ q_ = centers + ((size_t)(m) * NF + fdiv) * 3; \
    P##cx=q_[0]; P##cy=q_[1]; P##cz=q_[2]; \
} while (0)

#define NEI(P, MX, T0,T1,T2,T3,T4,T5,T6,T7,T8, S0,S1,S2,S3,S4,S5,S6,S7) do { \
    const float a1_ = P##T0*w0 + P##T1*w1 + P##T2*w2; \
    const float a2_ = P##T3*w0 + P##T4*w1 + P##T5*w2; \
    const float a3_ = P##T6*w0 + P##T7*w1 + P##T8*w2; \
    const float e2_ = a2_ - a1_, e3_ = a3_ - a1_; \
    const float v0_ = fmaf(bs##S0, e2_, fmaf(gs##S0, e3_, a1_)); \
    const float v1_ = fmaf(bs##S1, e2_, fmaf(gs##S1, e3_, a1_)); \
    const float v2_ = fmaf(bs##S2, e2_, fmaf(gs##S2, e3_, a1_)); \
    const float v3_ = fmaf(bs##S3, e2_, fmaf(gs##S3, e3_, a1_)); \
    const float v4_ = fmaf(bs##S4, e2_, fmaf(gs##S4, e3_, a1_)); \
    const float v5_ = fmaf(bs##S5, e2_, fmaf(gs##S5, e3_, a1_)); \
    const float v6_ = fmaf(bs##S6, e2_, fmaf(gs##S6, e3_, a1_)); \
    const float v7_ = fmaf(bs##S7, e2_, fmaf(gs##S7, e3_, a1_)); \
    const float p0_ = fmaxf(fmaxf(v0_, v1_), fmaxf(v2_, v3_)); \
    const float p1_ = fmaxf(fmaxf(v4_, v5_), fmaxf(v6_, v7_)); \
    MX = fmaxf(MX, fmaxf(p0_, p1_)); \
} while (0)

#define COMPUTE(P, m) do { \
    const float cdot_ = P##cx*w0 + P##cy*w1 + P##cz*w2; \
    float mx_ = -3.4e38f; \
    NEI(P, mx_,  0, 1, 2, 3, 4, 5, 6, 7, 8,    0,3,6,9,12,15,18,21); \
    NEI(P, mx_,  9,10,11,12,13,14,15,16,17,    1,4,7,10,13,16,19,22); \
    NEI(P, mx_, 18,19,20,21,22,23,24,25,26,    2,5,8,11,14,17,20,23); \
    out[((size_t)(m) * NF + fdiv) * NK + lane] = fmaxf(mx_ + (bk - cdot_), 0.0f); \
} while (0)

__global__ __launch_bounds__(256, 4) void conv_surface_kernel(
    const float* __restrict__ centers,   // [M,F,3]
    const float* __restrict__ nc,        // [M,F,3,3,3]
    const float* __restrict__ beta,      // [F,24]
    const float* __restrict__ gammav,    // [F,24]
    const float* __restrict__ W,         // [64,3]
    const float* __restrict__ b,         // [64]
    float* __restrict__ out)             // [M,F,64]
{
    const int tid  = threadIdx.x;
    const int lane = tid & 63;
    const int fdiv = blockIdx.x * 4 + (tid >> 6);   // divergent on purpose -> VMEM
    const int funi = __builtin_amdgcn_readfirstlane(fdiv);  // uniform -> SMEM

    // beta/gamma: uniform SGPR-resident, loaded once, reused for all 8 meshes
    const float4* __restrict__ bp4 = (const float4*)(beta   + (size_t)funi * 24);
    const float4* __restrict__ gp4 = (const float4*)(gammav + (size_t)funi * 24);
    const float4 bq0=bp4[0], bq1=bp4[1], bq2=bp4[2], bq3=bp4[3], bq4=bp4[4], bq5=bp4[5];
    const float4 gq0=gp4[0], gq1=gp4[1], gq2=gp4[2], gq3=gp4[3], gq4=gp4[4], gq5=gp4[5];
    const float bs0 =bq0.x, bs1 =bq0.y, bs2 =bq0.z, bs3 =bq0.w;
    const float bs4 =bq1.x, bs5 =bq1.y, bs6 =bq1.z, bs7 =bq1.w;
    const float bs8 =bq2.x, bs9 =bq2.y, bs10=bq2.z, bs11=bq2.w;
    const float bs12=bq3.x, bs13=bq3.y, bs14=bq3.z, bs15=bq3.w;
    const float bs16=bq4.x, bs17=bq4.y, bs18=bq4.z, bs19=bq4.w;
    const float bs20=bq5.x, bs21=bq5.y, bs22=bq5.z, bs23=bq5.w;
    const float gs0 =gq0.x, gs1 =gq0.y, gs2 =gq0.z, gs3 =gq0.w;
    const float gs4 =gq1.x, gs5 =gq1.y, gs6 =gq1.z, gs7 =gq1.w;
    const float gs8 =gq2.x, gs9 =gq2.y, gs10=gq2.z, gs11=gq2.w;
    const float gs12=gq3.x, gs13=gq3.y, gs14=gq3.z, gs15=gq3.w;
    const float gs16=gq4.x, gs17=gq4.y, gs18=gq4.z, gs19=gq4.w;
    const float gs20=gq5.x, gs21=gq5.y, gs22=gq5.z, gs23=gq5.w;

    // per-lane kernel weights
    const float w0 = W[lane * 3 + 0];
    const float w1 = W[lane * 3 + 1];
    const float w2 = W[lane * 3 + 2];
    const float bk = b[lane];

    DECL_SET(A)
    DECL_SET(B)

    LOADC(A, 0);
#pragma unroll 1
    for (int mm = 0; mm < 4; ++mm) {
        const int m0 = 2 * mm, m1 = 2 * mm + 1;
        LOADC(B, m1);                 // prefetch m1 while computing m0
        COMPUTE(A, m0);
        LOADC(A, (m0 + 2) & 7);       // prefetch m0+2 (mm=3: dead-safe reload)
        COMPUTE(B, m1);
    }
}

extern "C" void kernel_launch(void* const* d_in, const int* in_sizes, int n_in,
                              void* d_out, int out_size, void* d_ws, size_t ws_size,
                              hipStream_t stream) {
    const float* centers = (const float*)d_in[0];
    // d_in[1] = ring_n  (unused by the reference math)
    const float* nc      = (const float*)d_in[2];
    // d_in[3] = alpha   (unused: alpha = 1 - beta - gamma)
    const float* beta    = (const float*)d_in[4];
    const float* gammav  = (const float*)d_in[5];
    const float* W       = (const float*)d_in[6];
    const float* b       = (const float*)d_in[7];
    float* out = (float*)d_out;

    dim3 grid(NF / 4), block(256);   // one wave per face
    hipLaunchKernelGGL(conv_surface_kernel, grid, block, 0, stream,
                       centers, nc, beta, gammav, W, b, out);
}